// Round 16
// baseline (161.887 us; speedup 1.0000x reference)
//
#include <hip/hip_runtime.h>
#include <math.h>

#define VSZ 50000
#define VPAD 50176           // 98 chunks x 512 cols, all full
#define DD  128
#define BB  2048
#define CC  20
#define E2  256   // 2*D

// logits kernel tiling: 98 chunks x 16 row-blocks; 16 steps x 32 cols per chunk
#define NCHK 98
#define CH_COLS 512
#define NRB 16
#define NWG (NCHK * NRB)     // 1568, % 8 == 0
#define TSTEP 16             // steps per chunk
#define TILE_B 8192          // bytes per stage (32 cols x 256 B)

typedef short short8 __attribute__((ext_vector_type(8)));
typedef float f32x4  __attribute__((ext_vector_type(4)));

#define LOG2E 1.44269504f

__device__ __forceinline__ float softplusf(float x) {
  if (x > 20.f) return x;
  if (x < -20.f) return __expf(x);
  return log1pf(__expf(x));
}

__device__ __forceinline__ unsigned short f2bf(float f) {
  unsigned u = __float_as_uint(f);
  u = (u + 0x7fffu + ((u >> 16) & 1u)) >> 16;   // RNE
  return (unsigned short)u;
}

__device__ __forceinline__ float bf2f(unsigned short s) {
  return __uint_as_float(((unsigned)s) << 16);
}

__device__ __forceinline__ void gload_lds16(const void* g, void* l) {
  __builtin_amdgcn_global_load_lds(
      (const __attribute__((address_space(1))) unsigned int*)g,
      (__attribute__((address_space(3))) unsigned int*)l, 16, 0, 0);
}

// ---------------- convert fp32 -> bf16 tables + ebv table + zero S/pad ----------------
#define NV4 1600000
#define NE4 16384
#define NL4 8192
__global__ __launch_bounds__(256) void convert_all_kernel(
    const float* __restrict__ Wv, const float* __restrict__ We,
    const float* __restrict__ Wl, const float* __restrict__ Wsc,
    const float* __restrict__ b_vocab,
    ushort4* __restrict__ wv_bf, ushort4* __restrict__ we_bf,
    ushort4* __restrict__ wls_bf, float* __restrict__ ebv_g,
    float* __restrict__ S)
{
  const int gtid = blockIdx.x * 256 + threadIdx.x;
  const int stride = gridDim.x * 256;
  if (gtid < BB) S[gtid] = 0.f;
  if (gtid < (VPAD - VSZ) * 32) {
    ushort4 z; z.x = 0; z.y = 0; z.z = 0; z.w = 0;
    wv_bf[(size_t)VSZ * 32 + gtid] = z;
  }
  for (int idx = gtid; idx < VPAD; idx += stride)
    ebv_g[idx] = (idx < VSZ) ? exp2f(b_vocab[idx] * LOG2E) : 0.f;
  const int total = NV4 + NE4 + 2 * NL4;
  for (int idx = gtid; idx < total; idx += stride) {
    const float4* src; ushort4* dst; int off;
    if (idx < NV4)                   { src = (const float4*)Wv;  dst = wv_bf;  off = idx; }
    else if (idx < NV4 + NE4)        { src = (const float4*)We;  dst = we_bf;  off = idx - NV4; }
    else if (idx < NV4 + NE4 + NL4)  { src = (const float4*)Wl;  dst = wls_bf; off = idx - NV4 - NE4; }
    else { src = (const float4*)Wsc; dst = wls_bf + NL4;         off = idx - NV4 - NE4 - NL4; }
    float4 v = src[off];
    ushort4 o;
    o.x = f2bf(v.x); o.y = f2bf(v.y); o.z = f2bf(v.z); o.w = f2bf(v.w);
    dst[off] = o;
  }
}

// ---------------- encoder GEMM (MFMA), LDS-staged A, 2 b's per block ----------------
__global__ __launch_bounds__(256) void enc_mfma_kernel(
    const int* __restrict__ center_id, const int* __restrict__ context_ids,
    const float* __restrict__ embeddings,
    const unsigned short* __restrict__ we_bf, const float* __restrict__ b_enc,
    unsigned short* __restrict__ h_bf)
{
  const int b0   = blockIdx.x * 2;
  const int tid  = threadIdx.x;
  const int wave = tid >> 6, lane = tid & 63;
  const int lr = lane & 15;
  const int lk = lane >> 4;

  __shared__ __align__(16) unsigned short ebd[2][21][136];

  for (int i = tid; i < 2 * 21 * 32; i += 256) {
    const int bb = i / (21 * 32), r = (i >> 5) % 21, q = i & 31;
    const int src = (r < CC) ? context_ids[(b0 + bb) * CC + r] : center_id[b0 + bb];
    float4 v = ((const float4*)(embeddings + (size_t)src * DD))[q];
    ushort4 o;
    o.x = f2bf(v.x); o.y = f2bf(v.y); o.z = f2bf(v.z); o.w = f2bf(v.w);
    *(ushort4*)&ebd[bb][r][q * 4] = o;
  }
  __syncthreads();

  f32x4 acc[2][2][4];   // [b][row-tile][col-tile]
  #pragma unroll
  for (int bb = 0; bb < 2; bb++)
    #pragma unroll
    for (int rt = 0; rt < 2; rt++)
      #pragma unroll
      for (int ct = 0; ct < 4; ct++) acc[bb][rt][ct] = (f32x4){0.f, 0.f, 0.f, 0.f};

  const bool r1ok = (16 + lr) < CC;

  #pragma unroll
  for (int step = 0; step < 4; step++) {
    const int k0 = step * 32 + lk * 8;
    short8 a0 = *(const short8*)&ebd[0][20][k0];
    short8 a1 = *(const short8*)&ebd[1][20][k0];
    #pragma unroll
    for (int ct = 0; ct < 4; ct++) {
      const int e = (wave * 4 + ct) * 16 + lr;
      short8 w = *(const short8*)(we_bf + (size_t)e * E2 + k0);
      acc[0][0][ct] = __builtin_amdgcn_mfma_f32_16x16x32_bf16(a0, w, acc[0][0][ct], 0, 0, 0);
      acc[0][1][ct] = __builtin_amdgcn_mfma_f32_16x16x32_bf16(a0, w, acc[0][1][ct], 0, 0, 0);
      acc[1][0][ct] = __builtin_amdgcn_mfma_f32_16x16x32_bf16(a1, w, acc[1][0][ct], 0, 0, 0);
      acc[1][1][ct] = __builtin_amdgcn_mfma_f32_16x16x32_bf16(a1, w, acc[1][1][ct], 0, 0, 0);
    }
  }
  #pragma unroll
  for (int step = 4; step < 8; step++) {
    const int k0 = step * 32 + lk * 8;
    const int kk = k0 - DD;
    short8 a00 = *(const short8*)&ebd[0][lr][kk];
    short8 a01 = r1ok ? *(const short8*)&ebd[0][16 + lr][kk] : (short8)0;
    short8 a10 = *(const short8*)&ebd[1][lr][kk];
    short8 a11 = r1ok ? *(const short8*)&ebd[1][16 + lr][kk] : (short8)0;
    #pragma unroll
    for (int ct = 0; ct < 4; ct++) {
      const int e = (wave * 4 + ct) * 16 + lr;
      short8 w = *(const short8*)(we_bf + (size_t)e * E2 + k0);
      acc[0][0][ct] = __builtin_amdgcn_mfma_f32_16x16x32_bf16(a00, w, acc[0][0][ct], 0, 0, 0);
      acc[0][1][ct] = __builtin_amdgcn_mfma_f32_16x16x32_bf16(a01, w, acc[0][1][ct], 0, 0, 0);
      acc[1][0][ct] = __builtin_amdgcn_mfma_f32_16x16x32_bf16(a10, w, acc[1][0][ct], 0, 0, 0);
      acc[1][1][ct] = __builtin_amdgcn_mfma_f32_16x16x32_bf16(a11, w, acc[1][1][ct], 0, 0, 0);
    }
  }

  float be[4];
  #pragma unroll
  for (int ct = 0; ct < 4; ct++) be[ct] = b_enc[(wave * 4 + ct) * 16 + lr];
  #pragma unroll
  for (int bb = 0; bb < 2; bb++) {
    float p[4] = {0.f, 0.f, 0.f, 0.f};
    #pragma unroll
    for (int rt = 0; rt < 2; rt++) {
      #pragma unroll
      for (int j = 0; j < 4; j++) {
        const int row = rt * 16 + lk * 4 + j;
        if (row < CC) {
          #pragma unroll
          for (int ct = 0; ct < 4; ct++) p[ct] += fmaxf(acc[bb][rt][ct][j] + be[ct], 0.f);
        }
      }
    }
    #pragma unroll
    for (int ct = 0; ct < 4; ct++) {
      p[ct] += __shfl_xor(p[ct], 16);
      p[ct] += __shfl_xor(p[ct], 32);
    }
    if (lk == 0) {
      #pragma unroll
      for (int ct = 0; ct < 4; ct++)
        h_bf[(size_t)(b0 + bb) * E2 + (wave * 4 + ct) * 16 + lr] = f2bf(p[ct]);
    }
  }
}

// ---------------- ls_post: [loc;scale] GEMM + z + KL + context-logit sums ----------------
__global__ __launch_bounds__(256) void ls_post_kernel(
    const int* __restrict__ center_id, const int* __restrict__ context_ids,
    const float* __restrict__ eps,
    const float* __restrict__ prior_locs, const float* __restrict__ prior_scales,
    const unsigned short* __restrict__ h_bf, const unsigned short* __restrict__ wls_bf,
    const float* __restrict__ b_loc, const float* __restrict__ b_scale,
    const unsigned short* __restrict__ wv_bf, const float* __restrict__ b_vocab,
    unsigned short* __restrict__ zbf, float* __restrict__ base)
{
  const int b0   = blockIdx.x * 8;
  const int tid  = threadIdx.x;
  const int wave = tid >> 6, lane = tid & 63;
  const int lr = lane & 15, lk = lane >> 4;

  __shared__ __align__(16) float loc_s[8][DD];
  __shared__ __align__(16) float scale_s[8][DD];
  __shared__ __align__(16) float zsh[8][DD];
  __shared__ float klv[8], ctxacc[8];

  if (tid < 8) ctxacc[tid] = 0.f;

  f32x4 acc[4];
  #pragma unroll
  for (int ct = 0; ct < 4; ct++) acc[ct] = (f32x4){0.f, 0.f, 0.f, 0.f};

  #pragma unroll
  for (int step = 0; step < 8; step++) {
    const int k0 = step * 32 + lk * 8;
    short8 a = (lr < 8) ? *(const short8*)(h_bf + (size_t)(b0 + lr) * E2 + k0) : (short8)0;
    #pragma unroll
    for (int ct = 0; ct < 4; ct++) {
      const int o = (wave * 4 + ct) * 16 + lr;
      short8 w = *(const short8*)(wls_bf + (size_t)o * E2 + k0);
      acc[ct] = __builtin_amdgcn_mfma_f32_16x16x32_bf16(a, w, acc[ct], 0, 0, 0);
    }
  }
  #pragma unroll
  for (int ct = 0; ct < 4; ct++) {
    const int o = (wave * 4 + ct) * 16 + lr;
    #pragma unroll
    for (int j = 0; j < 4; j++) {
      const int br = lk * 4 + j;
      if (br < 8) {
        const float v = acc[ct][j];
        if (o < DD) loc_s[br][o] = v + b_loc[o];
        else        scale_s[br][o - DD] = softplusf(v + b_scale[o - DD]);
      }
    }
  }
  __syncthreads();

  if (tid < 128) {
    const int bi = tid >> 4, d0 = (tid & 15) * 8;
    const int cid = center_id[b0 + bi];
    const float* pl = prior_locs  + (size_t)cid * DD + d0;
    const float* ps = prior_scales + (size_t)cid * DD + d0;
    float kacc = 0.f;
    short8 zb;
    #pragma unroll
    for (int q = 0; q < 8; q++) {
      const float loc = loc_s[bi][d0 + q], scl = scale_s[bi][d0 + q];
      const float z = fmaf(scl, eps[d0 + q], loc);
      zsh[bi][d0 + q] = z;
      zb[q] = (short)f2bf(z * LOG2E);
      const float ploc = pl[q];
      const float pscl = softplusf(ps[q]);
      const float dd = loc - ploc;
      kacc += logf(pscl / scl) + (scl * scl + dd * dd) / (2.f * pscl * pscl) - 0.5f;
    }
    *(short8*)(zbf + (size_t)(b0 + bi) * DD + d0) = zb;
    #pragma unroll
    for (int off = 1; off < 16; off <<= 1) kacc += __shfl_xor(kacc, off, 16);
    if ((tid & 15) == 0) klv[bi] = kacc;
  }
  __syncthreads();

  for (int idx = tid; idx < 8 * CC; idx += 256) {
    const int db = idx / CC, c = idx - db * CC;
    const int vid = context_ids[(size_t)(b0 + db) * CC + c];
    const unsigned short* wr = wv_bf + (size_t)vid * DD;
    float dsum = b_vocab[vid];
    #pragma unroll 4
    for (int q = 0; q < 16; q++) {
      short8 w8 = *(const short8*)(wr + q * 8);
      #pragma unroll
      for (int j = 0; j < 8; j++)
        dsum = fmaf(bf2f((unsigned short)w8[j]), zsh[db][q * 8 + j], dsum);
    }
    atomicAdd(&ctxacc[db], dsum);
  }
  __syncthreads();

  if (tid < 8) base[b0 + tid] = klv[tid] - ctxacc[tid];
}

// ---------------- logits GEMM: lean-body counted-vmcnt, 16x32-col steps ----------------
// R15 body (static lp offsets) + 3 x 8 KB LDS buffers, 2-deep stage pipeline:
// per step s_waitcnt vmcnt(2) (own stage's 2 loads) -> s_barrier -> issue
// stage t+2 -> compute. NO full drain mid-loop. In-loop VMEM = stage only
// (ebv from an LDS table filled before the prologue drain).
__global__ __launch_bounds__(256) void logits_mfma_kernel(
    const unsigned short* __restrict__ zbf, const unsigned short* __restrict__ wbf,
    const float* __restrict__ ebv_g, float* __restrict__ S)
{
  __shared__ __align__(16) char lds3[3][TILE_B];
  __shared__ float ebv_s[CH_COLS];

  const int tid  = threadIdx.x;
  const int wave = tid >> 6, lane = tid & 63;
  const int lr = lane & 15;
  const int lk = lane >> 4;

  // bijective XCD swizzle: 1568 % 8 == 0, 196 blocks per XCD
  const int swz = (blockIdx.x & 7) * (NWG / 8) + (blockIdx.x >> 3);
  const int ch  = swz >> 4;          // 0..97
  const int rb  = swz & 15;
  const size_t cbase = (size_t)ch * (CH_COLS * 256);
  const int row0 = rb * 128 + wave * 32;

  // A fragments (8 global loads) — before the prologue drain
  short8 a[2][4];
  #pragma unroll
  for (int rt = 0; rt < 2; rt++)
    #pragma unroll
    for (int kk = 0; kk < 4; kk++)
      a[rt][kk] = *(const short8*)(zbf + (size_t)(row0 + rt * 16 + lr) * DD + kk * 32 + lk * 8);

  // ebv table into LDS (1 float2 load/thread) — before the drain
  *(float2*)&ebv_s[tid * 2] = *(const float2*)&ebv_g[ch * CH_COLS + tid * 2];

  // per-lane LDS read base pointers (static offsets under full unroll)
  const char* lp[4];
  #pragma unroll
  for (int kk = 0; kk < 4; kk++)
    lp[kk] = &lds3[0][0] + lr * 256 + (((kk * 4 + lk) ^ lr) << 4);

  __syncthreads();   // full drain: A-frags + ebv retired, FIFO clean

  // stage: 2 issues/wave; issue i_ covers cols wave*8 + i_*4 + (lane>>4).
  // LDS linear; pre-swizzled global source: byte = c*256 + ((u^(c&15))*16).
#define STAGE(buf, st) do {                                                    \
    _Pragma("unroll")                                                          \
    for (int i_ = 0; i_ < 2; i_++) {                                           \
      const int c_ = wave * 8 + i_ * 4 + (lane >> 4);                          \
      const size_t go_ = cbase + (size_t)(st) * TILE_B +                       \
                         (size_t)c_ * 256 + (size_t)(((lane & 15) ^ (c_ & 15)) << 4); \
      gload_lds16((const char*)wbf + go_, &lds3[(buf)][wave * 2048 + i_ * 1024]); \
    }                                                                          \
  } while (0)

  STAGE(0, 0);
  STAGE(1, 1);

  float Ssum[2][4];
  #pragma unroll
  for (int rt = 0; rt < 2; rt++)
    #pragma unroll
    for (int j = 0; j < 4; j++) Ssum[rt][j] = 0.f;

  #pragma unroll
  for (int t = 0; t < TSTEP; t++) {
    if (t < TSTEP - 1) asm volatile("s_waitcnt vmcnt(2)" ::: "memory");
    else               asm volatile("s_waitcnt vmcnt(0)" ::: "memory");
    __builtin_amdgcn_s_barrier();
    if (t + 2 < TSTEP) STAGE((t + 2) % 3, t + 2);

    float ebv[2];
    #pragma unroll
    for (int ct = 0; ct < 2; ct++) ebv[ct] = ebv_s[t * 32 + ct * 16 + lr];

    #pragma unroll
    for (int ct = 0; ct < 2; ct++) {
      short8 bf[4];
      #pragma unroll
      for (int kk = 0; kk < 4; kk++)
        bf[kk] = *(const short8*)(lp[kk] + (t % 3) * TILE_B + ct * 4096);
      f32x4 acc0 = (f32x4){0.f, 0.f, 0.f, 0.f};
      f32x4 acc1 = (f32x4){0.f, 0.f, 0.f, 0.f};
      #pragma unroll
      for (int kk = 0; kk < 4; kk++) {
        acc0 = __builtin_amdgcn_mfma_f32_16x16x32_bf16(a[0][kk], bf[kk], acc0, 0, 0, 0);
        acc1 = __builtin_amdgcn_mfma_f32_16x16x32_bf16(a[1][kk], bf[kk], acc1, 0, 0, 0);
      }
      #pragma unroll
      for (int j = 0; j < 4; j++) {
        Ssum[0][j] = fmaf(exp2f(acc0[j]), ebv[ct], Ssum[0][j]);
        Ssum[1][j] = fmaf(exp2f(acc1[j]), ebv[ct], Ssum[1][j]);
      }
    }
  }
#undef STAGE

  #pragma unroll
  for (int rt = 0; rt < 2; rt++)
    #pragma unroll
    for (int j = 0; j < 4; j++) {
      float s = Ssum[rt][j];
      s += __shfl_xor(s, 1, 16);
      s += __shfl_xor(s, 2, 16);
      s += __shfl_xor(s, 4, 16);
      s += __shfl_xor(s, 8, 16);
      if (lr == 0) atomicAdd(&S[row0 + rt * 16 + lk * 4 + j], s);
    }
}

// ---------------- finalize ----------------
__global__ __launch_bounds__(256) void fin_kernel(
    const float* __restrict__ S, const float* __restrict__ base, float* __restrict__ out)
{
  const int t = threadIdx.x;
  float local = 0.f;
  for (int b = t; b < BB; b += 256)
    local += base[b] + (float)CC * logf(S[b]);
  __shared__ float red[256];
  red[t] = local;
  __syncthreads();
  for (int off = 128; off; off >>= 1) {
    if (t < off) red[t] += red[t + off];
    __syncthreads();
  }
  if (t == 0) out[0] = red[0] / (float)BB;
}

extern "C" void kernel_launch(void* const* d_in, const int* in_sizes, int n_in,
                              void* d_out, int out_size, void* d_ws, size_t ws_size,
                              hipStream_t stream) {
  const int*   center_id    = (const int*)d_in[0];
  const int*   context_ids  = (const int*)d_in[1];
  const float* eps          = (const float*)d_in[2];
  const float* embeddings   = (const float*)d_in[3];
  const float* prior_locs   = (const float*)d_in[4];
  const float* prior_scales = (const float*)d_in[5];
  const float* W_enc        = (const float*)d_in[6];
  const float* b_enc        = (const float*)d_in[7];
  const float* W_loc        = (const float*)d_in[8];
  const float* b_loc        = (const float*)d_in[9];
  const float* W_scale      = (const float*)d_in[10];
  const float* b_scale      = (const float*)d_in[11];
  const float* W_vocab      = (const float*)d_in[12];
  const float* b_vocab      = (const float*)d_in[13];
  float* out = (float*)d_out;

  // ws layout (bytes), total 14,897,152:
  //   wv_bf  : 12,845,056  (VPAD*256; rows >= 50000 zeroed)
  //   we_bf  :    131,072
  //   wls_bf :    131,072
  //   h_bf   :  1,048,576
  //   zbf    :    524,288  (z * log2e, bf16)
  //   S      :      8,192
  //   base   :      8,192
  //   ebv_g  :    200,704  (exp(b_vocab), fp32; 0 on pad)
  char* ws = (char*)d_ws;
  unsigned short* wv_bf  = (unsigned short*)(ws);
  unsigned short* we_bf  = (unsigned short*)(ws + 12845056);
  unsigned short* wls_bf = (unsigned short*)(ws + 12845056 + 131072);
  unsigned short* h_bf   = (unsigned short*)(ws + 12845056 + 2 * 131072);
  unsigned short* zbf    = (unsigned short*)(ws + 12845056 + 2 * 131072 + 1048576);
  float*          S      = (float*)(ws + 12845056 + 2 * 131072 + 1048576 + 524288);
  float*          base   = (float*)(ws + 12845056 + 2 * 131072 + 1048576 + 524288 + 8192);
  float*          ebv_g  = (float*)(ws + 12845056 + 2 * 131072 + 1048576 + 524288 + 2 * 8192);

  hipLaunchKernelGGL(convert_all_kernel, dim3(1024), dim3(256), 0, stream,
                     W_vocab, W_enc, W_loc, W_scale, b_vocab,
                     (ushort4*)wv_bf, (ushort4*)we_bf, (ushort4*)wls_bf, ebv_g, S);
  hipLaunchKernelGGL(enc_mfma_kernel, dim3(BB / 2), dim3(256), 0, stream,
                     center_id, context_ids, embeddings, we_bf, b_enc, h_bf);
  hipLaunchKernelGGL(ls_post_kernel, dim3(BB / 8), dim3(256), 0, stream,
                     center_id, context_ids, eps, prior_locs, prior_scales,
                     h_bf, wls_bf, b_loc, b_scale, wv_bf, b_vocab, zbf, base);
  hipLaunchKernelGGL(logits_mfma_kernel, dim3(NWG), dim3(256), 0, stream,
                     zbf, wv_bf, ebv_g, S);
  hipLaunchKernelGGL(fin_kernel, dim3(1), dim3(256), 0, stream, S, base, out);
}

// Round 17
// 113.197 us; speedup vs baseline: 1.4301x; 1.4301x over previous
//
#include <hip/hip_runtime.h>
#include <math.h>

#define VSZ 50000
#define VPAD 50176           // 98 chunks x 512 cols, all full
#define DD  128
#define BB  2048
#define CC  20
#define E2  256   // 2*D

// logits kernel tiling (R7 geometry)
#define NCHK 98
#define CH_COLS 512
#define NRB 16               // row-blocks (2048 / 128)
#define NWG (NCHK * NRB)     // 1568 blocks, % 8 == 0

typedef short short8 __attribute__((ext_vector_type(8)));
typedef float f32x4  __attribute__((ext_vector_type(4)));

#define LOG2E 1.44269504f

__device__ __forceinline__ float softplusf(float x) {
  if (x > 20.f) return x;
  if (x < -20.f) return __expf(x);
  return log1pf(__expf(x));
}

__device__ __forceinline__ unsigned short f2bf(float f) {
  unsigned u = __float_as_uint(f);
  u = (u + 0x7fffu + ((u >> 16) & 1u)) >> 16;   // RNE
  return (unsigned short)u;
}

__device__ __forceinline__ float bf2f(unsigned short s) {
  return __uint_as_float(((unsigned)s) << 16);
}

__device__ __forceinline__ void gload_lds16(const void* g, void* l) {
  __builtin_amdgcn_global_load_lds(
      (const __attribute__((address_space(1))) unsigned int*)g,
      (__attribute__((address_space(3))) unsigned int*)l, 16, 0, 0);
}

// ---------------- convert fp32 -> bf16 tables + ebv table + zero S/pad ----------------
#define NV4 1600000
#define NE4 16384
#define NL4 8192
__global__ __launch_bounds__(256) void convert_all_kernel(
    const float* __restrict__ Wv, const float* __restrict__ We,
    const float* __restrict__ Wl, const float* __restrict__ Wsc,
    const float* __restrict__ b_vocab,
    ushort4* __restrict__ wv_bf, ushort4* __restrict__ we_bf,
    ushort4* __restrict__ wls_bf, float* __restrict__ ebv_g,
    float* __restrict__ S)
{
  const int gtid = blockIdx.x * 256 + threadIdx.x;
  const int stride = gridDim.x * 256;
  if (gtid < BB) S[gtid] = 0.f;
  // zero the 176 pad rows of wv_bf: (VPAD-VSZ)*32 = 5632 ushort4
  if (gtid < (VPAD - VSZ) * 32) {
    ushort4 z; z.x = 0; z.y = 0; z.z = 0; z.w = 0;
    wv_bf[(size_t)VSZ * 32 + gtid] = z;
  }
  // exp(b_vocab) table (pad cols -> 0)
  for (int idx = gtid; idx < VPAD; idx += stride)
    ebv_g[idx] = (idx < VSZ) ? exp2f(b_vocab[idx] * LOG2E) : 0.f;
  const int total = NV4 + NE4 + 2 * NL4;
  for (int idx = gtid; idx < total; idx += stride) {
    const float4* src; ushort4* dst; int off;
    if (idx < NV4)                   { src = (const float4*)Wv;  dst = wv_bf;  off = idx; }
    else if (idx < NV4 + NE4)        { src = (const float4*)We;  dst = we_bf;  off = idx - NV4; }
    else if (idx < NV4 + NE4 + NL4)  { src = (const float4*)Wl;  dst = wls_bf; off = idx - NV4 - NE4; }
    else { src = (const float4*)Wsc; dst = wls_bf + NL4;         off = idx - NV4 - NE4 - NL4; }
    float4 v = src[off];
    ushort4 o;
    o.x = f2bf(v.x); o.y = f2bf(v.y); o.z = f2bf(v.z); o.w = f2bf(v.w);
    dst[off] = o;
  }
}

// ---------------- encoder GEMM (MFMA), LDS-staged A, 2 b's per block ----------------
__global__ __launch_bounds__(256) void enc_mfma_kernel(
    const int* __restrict__ center_id, const int* __restrict__ context_ids,
    const float* __restrict__ embeddings,
    const unsigned short* __restrict__ we_bf, const float* __restrict__ b_enc,
    unsigned short* __restrict__ h_bf)
{
  const int b0   = blockIdx.x * 2;
  const int tid  = threadIdx.x;
  const int wave = tid >> 6, lane = tid & 63;
  const int lr = lane & 15;
  const int lk = lane >> 4;

  __shared__ __align__(16) unsigned short ebd[2][21][136];

  for (int i = tid; i < 2 * 21 * 32; i += 256) {
    const int bb = i / (21 * 32), r = (i >> 5) % 21, q = i & 31;
    const int src = (r < CC) ? context_ids[(b0 + bb) * CC + r] : center_id[b0 + bb];
    float4 v = ((const float4*)(embeddings + (size_t)src * DD))[q];
    ushort4 o;
    o.x = f2bf(v.x); o.y = f2bf(v.y); o.z = f2bf(v.z); o.w = f2bf(v.w);
    *(ushort4*)&ebd[bb][r][q * 4] = o;
  }
  __syncthreads();

  f32x4 acc[2][2][4];   // [b][row-tile][col-tile]
  #pragma unroll
  for (int bb = 0; bb < 2; bb++)
    #pragma unroll
    for (int rt = 0; rt < 2; rt++)
      #pragma unroll
      for (int ct = 0; ct < 4; ct++) acc[bb][rt][ct] = (f32x4){0.f, 0.f, 0.f, 0.f};

  const bool r1ok = (16 + lr) < CC;

  #pragma unroll
  for (int step = 0; step < 4; step++) {
    const int k0 = step * 32 + lk * 8;
    short8 a0 = *(const short8*)&ebd[0][20][k0];
    short8 a1 = *(const short8*)&ebd[1][20][k0];
    #pragma unroll
    for (int ct = 0; ct < 4; ct++) {
      const int e = (wave * 4 + ct) * 16 + lr;
      short8 w = *(const short8*)(we_bf + (size_t)e * E2 + k0);
      acc[0][0][ct] = __builtin_amdgcn_mfma_f32_16x16x32_bf16(a0, w, acc[0][0][ct], 0, 0, 0);
      acc[0][1][ct] = __builtin_amdgcn_mfma_f32_16x16x32_bf16(a0, w, acc[0][1][ct], 0, 0, 0);
      acc[1][0][ct] = __builtin_amdgcn_mfma_f32_16x16x32_bf16(a1, w, acc[1][0][ct], 0, 0, 0);
      acc[1][1][ct] = __builtin_amdgcn_mfma_f32_16x16x32_bf16(a1, w, acc[1][1][ct], 0, 0, 0);
    }
  }
  #pragma unroll
  for (int step = 4; step < 8; step++) {
    const int k0 = step * 32 + lk * 8;
    const int kk = k0 - DD;
    short8 a00 = *(const short8*)&ebd[0][lr][kk];
    short8 a01 = r1ok ? *(const short8*)&ebd[0][16 + lr][kk] : (short8)0;
    short8 a10 = *(const short8*)&ebd[1][lr][kk];
    short8 a11 = r1ok ? *(const short8*)&ebd[1][16 + lr][kk] : (short8)0;
    #pragma unroll
    for (int ct = 0; ct < 4; ct++) {
      const int e = (wave * 4 + ct) * 16 + lr;
      short8 w = *(const short8*)(we_bf + (size_t)e * E2 + k0);
      acc[0][0][ct] = __builtin_amdgcn_mfma_f32_16x16x32_bf16(a00, w, acc[0][0][ct], 0, 0, 0);
      acc[0][1][ct] = __builtin_amdgcn_mfma_f32_16x16x32_bf16(a01, w, acc[0][1][ct], 0, 0, 0);
      acc[1][0][ct] = __builtin_amdgcn_mfma_f32_16x16x32_bf16(a10, w, acc[1][0][ct], 0, 0, 0);
      acc[1][1][ct] = __builtin_amdgcn_mfma_f32_16x16x32_bf16(a11, w, acc[1][1][ct], 0, 0, 0);
    }
  }

  float be[4];
  #pragma unroll
  for (int ct = 0; ct < 4; ct++) be[ct] = b_enc[(wave * 4 + ct) * 16 + lr];
  #pragma unroll
  for (int bb = 0; bb < 2; bb++) {
    float p[4] = {0.f, 0.f, 0.f, 0.f};
    #pragma unroll
    for (int rt = 0; rt < 2; rt++) {
      #pragma unroll
      for (int j = 0; j < 4; j++) {
        const int row = rt * 16 + lk * 4 + j;
        if (row < CC) {
          #pragma unroll
          for (int ct = 0; ct < 4; ct++) p[ct] += fmaxf(acc[bb][rt][ct][j] + be[ct], 0.f);
        }
      }
    }
    #pragma unroll
    for (int ct = 0; ct < 4; ct++) {
      p[ct] += __shfl_xor(p[ct], 16);
      p[ct] += __shfl_xor(p[ct], 32);
    }
    if (lk == 0) {
      #pragma unroll
      for (int ct = 0; ct < 4; ct++)
        h_bf[(size_t)(b0 + bb) * E2 + (wave * 4 + ct) * 16 + lr] = f2bf(p[ct]);
    }
  }
}

// ---------------- ls_post: [loc;scale] GEMM + z + KL + context-logit sums ----------------
// zbf written PRE-SCALED by log2(e). ctx dots read wv_bf (bf16, half the bytes).
__global__ __launch_bounds__(256) void ls_post_kernel(
    const int* __restrict__ center_id, const int* __restrict__ context_ids,
    const float* __restrict__ eps,
    const float* __restrict__ prior_locs, const float* __restrict__ prior_scales,
    const unsigned short* __restrict__ h_bf, const unsigned short* __restrict__ wls_bf,
    const float* __restrict__ b_loc, const float* __restrict__ b_scale,
    const unsigned short* __restrict__ wv_bf, const float* __restrict__ b_vocab,
    unsigned short* __restrict__ zbf, float* __restrict__ base)
{
  const int b0   = blockIdx.x * 8;
  const int tid  = threadIdx.x;
  const int wave = tid >> 6, lane = tid & 63;
  const int lr = lane & 15, lk = lane >> 4;

  __shared__ __align__(16) float loc_s[8][DD];
  __shared__ __align__(16) float scale_s[8][DD];
  __shared__ __align__(16) float zsh[8][DD];
  __shared__ float klv[8], ctxacc[8];

  if (tid < 8) ctxacc[tid] = 0.f;

  f32x4 acc[4];
  #pragma unroll
  for (int ct = 0; ct < 4; ct++) acc[ct] = (f32x4){0.f, 0.f, 0.f, 0.f};

  #pragma unroll
  for (int step = 0; step < 8; step++) {
    const int k0 = step * 32 + lk * 8;
    short8 a = (lr < 8) ? *(const short8*)(h_bf + (size_t)(b0 + lr) * E2 + k0) : (short8)0;
    #pragma unroll
    for (int ct = 0; ct < 4; ct++) {
      const int o = (wave * 4 + ct) * 16 + lr;
      short8 w = *(const short8*)(wls_bf + (size_t)o * E2 + k0);
      acc[ct] = __builtin_amdgcn_mfma_f32_16x16x32_bf16(a, w, acc[ct], 0, 0, 0);
    }
  }
  #pragma unroll
  for (int ct = 0; ct < 4; ct++) {
    const int o = (wave * 4 + ct) * 16 + lr;
    #pragma unroll
    for (int j = 0; j < 4; j++) {
      const int br = lk * 4 + j;
      if (br < 8) {
        const float v = acc[ct][j];
        if (o < DD) loc_s[br][o] = v + b_loc[o];
        else        scale_s[br][o - DD] = softplusf(v + b_scale[o - DD]);
      }
    }
  }
  __syncthreads();

  if (tid < 128) {
    const int bi = tid >> 4, d0 = (tid & 15) * 8;
    const int cid = center_id[b0 + bi];
    const float* pl = prior_locs  + (size_t)cid * DD + d0;
    const float* ps = prior_scales + (size_t)cid * DD + d0;
    float kacc = 0.f;
    short8 zb;
    #pragma unroll
    for (int q = 0; q < 8; q++) {
      const float loc = loc_s[bi][d0 + q], scl = scale_s[bi][d0 + q];
      const float z = fmaf(scl, eps[d0 + q], loc);
      zsh[bi][d0 + q] = z;
      zb[q] = (short)f2bf(z * LOG2E);
      const float ploc = pl[q];
      const float pscl = softplusf(ps[q]);
      const float dd = loc - ploc;
      kacc += logf(pscl / scl) + (scl * scl + dd * dd) / (2.f * pscl * pscl) - 0.5f;
    }
    *(short8*)(zbf + (size_t)(b0 + bi) * DD + d0) = zb;
    #pragma unroll
    for (int off = 1; off < 16; off <<= 1) kacc += __shfl_xor(kacc, off, 16);
    if ((tid & 15) == 0) klv[bi] = kacc;
  }
  __syncthreads();

  for (int idx = tid; idx < 8 * CC; idx += 256) {
    const int db = idx / CC, c = idx - db * CC;
    const int vid = context_ids[(size_t)(b0 + db) * CC + c];
    const unsigned short* wr = wv_bf + (size_t)vid * DD;
    float dsum = b_vocab[vid];
    #pragma unroll 4
    for (int q = 0; q < 16; q++) {
      short8 w8 = *(const short8*)(wr + q * 8);
      #pragma unroll
      for (int j = 0; j < 8; j++)
        dsum = fmaf(bf2f((unsigned short)w8[j]), zsh[db][q * 8 + j], dsum);
    }
    atomicAdd(&ctxacc[db], dsum);
  }
  __syncthreads();

  if (tid < 8) base[b0 + tid] = klv[tid] - ctxacc[tid];
}

// ---------------- logits GEMM: R12 structure + static-offset LDS reads + ebv table ----------------
// Structure identical to the 63-us verified kernel; only address generation
// changed: 4 precomputed per-lane LDS base pointers, all 32 in-loop reads use
// compile-time offsets (buf*16384 + ct*4096 <= 28672, fits imm16); per-column
// exp(bias) comes from the precomputed ebv_g table (plain loads, no exp2/cmp).
__global__ __launch_bounds__(256) void logits_mfma_kernel(
    const unsigned short* __restrict__ zbf, const unsigned short* __restrict__ wbf,
    const float* __restrict__ ebv_g, float* __restrict__ S)
{
  __shared__ __align__(16) char lds[2][16384];

  const int tid  = threadIdx.x;
  const int wave = tid >> 6, lane = tid & 63;
  const int lr = lane & 15;
  const int lk = lane >> 4;

  // bijective XCD swizzle: 1568 % 8 == 0, 196 blocks per XCD
  const int swz = (blockIdx.x & 7) * (NWG / 8) + (blockIdx.x >> 3);
  const int ch  = swz >> 4;          // 0..97
  const int rb  = swz & 15;
  const size_t cbase = (size_t)ch * (CH_COLS * 256);
  const int row0 = rb * 128 + wave * 32;

  short8 a[2][4];
  #pragma unroll
  for (int rt = 0; rt < 2; rt++)
    #pragma unroll
    for (int kk = 0; kk < 4; kk++)
      a[rt][kk] = *(const short8*)(zbf + (size_t)(row0 + rt * 16 + lr) * DD + kk * 32 + lk * 8);

  // per-lane LDS read base pointers (static kk indices under full unroll)
  const char* lp[4];
  #pragma unroll
  for (int kk = 0; kk < 4; kk++)
    lp[kk] = &lds[0][0] + lr * 256 + (((kk * 4 + lk) ^ lr) << 4);

  // per-lane ebv base pointer
  const float* ebp = ebv_g + ch * CH_COLS + lr;

#define STAGE(buf, st) do {                                                    \
    _Pragma("unroll")                                                          \
    for (int i_ = 0; i_ < 4; i_++) {                                           \
      const int c_ = (wave * 4 + i_) * 4 + (lane >> 4);                        \
      const size_t go_ = cbase + (size_t)(st) * 16384 +                        \
                         (size_t)c_ * 256 + (size_t)(((lane & 15) ^ (c_ & 15)) << 4); \
      gload_lds16((const char*)wbf + go_, &lds[(buf)][(wave * 4 + i_) * 1024]);\
    }                                                                          \
  } while (0)

  STAGE(0, 0);

  float Ssum[2][4];
  #pragma unroll
  for (int rt = 0; rt < 2; rt++)
    #pragma unroll
    for (int j = 0; j < 4; j++) Ssum[rt][j] = 0.f;

  __syncthreads();   // drains prologue stage

  #pragma unroll
  for (int step = 0; step < 8; step++) {
    const int buf = step & 1;
    if (step + 1 < 8) STAGE(buf ^ 1, step + 1);

    float ebv[4];
    #pragma unroll
    for (int ct = 0; ct < 4; ct++) ebv[ct] = ebp[step * 64 + ct * 16];

    #pragma unroll
    for (int ct = 0; ct < 4; ct++) {
      short8 bf[4];
      #pragma unroll
      for (int kk = 0; kk < 4; kk++)
        bf[kk] = *(const short8*)(lp[kk] + buf * 16384 + ct * 4096);
      f32x4 acc0 = (f32x4){0.f, 0.f, 0.f, 0.f};
      f32x4 acc1 = (f32x4){0.f, 0.f, 0.f, 0.f};
      #pragma unroll
      for (int kk = 0; kk < 4; kk++) {
        acc0 = __builtin_amdgcn_mfma_f32_16x16x32_bf16(a[0][kk], bf[kk], acc0, 0, 0, 0);
        acc1 = __builtin_amdgcn_mfma_f32_16x16x32_bf16(a[1][kk], bf[kk], acc1, 0, 0, 0);
      }
      #pragma unroll
      for (int j = 0; j < 4; j++) {
        Ssum[0][j] = fmaf(exp2f(acc0[j]), ebv[ct], Ssum[0][j]);
        Ssum[1][j] = fmaf(exp2f(acc1[j]), ebv[ct], Ssum[1][j]);
      }
    }

    __syncthreads();
  }
#undef STAGE

  #pragma unroll
  for (int rt = 0; rt < 2; rt++)
    #pragma unroll
    for (int j = 0; j < 4; j++) {
      float s = Ssum[rt][j];
      s += __shfl_xor(s, 1, 16);
      s += __shfl_xor(s, 2, 16);
      s += __shfl_xor(s, 4, 16);
      s += __shfl_xor(s, 8, 16);
      if (lr == 0) atomicAdd(&S[row0 + rt * 16 + lk * 4 + j], s);
    }
}

// ---------------- finalize ----------------
__global__ __launch_bounds__(256) void fin_kernel(
    const float* __restrict__ S, const float* __restrict__ base, float* __restrict__ out)
{
  const int t = threadIdx.x;
  float local = 0.f;
  for (int b = t; b < BB; b += 256)
    local += base[b] + (float)CC * logf(S[b]);
  __shared__ float red[256];
  red[t] = local;
  __syncthreads();
  for (int off = 128; off; off >>= 1) {
    if (t < off) red[t] += red[t + off];
    __syncthreads();
  }
  if (t == 0) out[0] = red[0] / (float)BB;
}

extern "C" void kernel_launch(void* const* d_in, const int* in_sizes, int n_in,
                              void* d_out, int out_size, void* d_ws, size_t ws_size,
                              hipStream_t stream) {
  const int*   center_id    = (const int*)d_in[0];
  const int*   context_ids  = (const int*)d_in[1];
  const float* eps          = (const float*)d_in[2];
  const float* embeddings   = (const float*)d_in[3];
  const float* prior_locs   = (const float*)d_in[4];
  const float* prior_scales = (const float*)d_in[5];
  const float* W_enc        = (const float*)d_in[6];
  const float* b_enc        = (const float*)d_in[7];
  const float* W_loc        = (const float*)d_in[8];
  const float* b_loc        = (const float*)d_in[9];
  const float* W_scale      = (const float*)d_in[10];
  const float* b_scale      = (const float*)d_in[11];
  const float* W_vocab      = (const float*)d_in[12];
  const float* b_vocab      = (const float*)d_in[13];
  float* out = (float*)d_out;

  // ws layout (bytes), total 14,897,152:
  //   wv_bf  : 12,845,056  (VPAD*256; rows >= 50000 zeroed)
  //   we_bf  :    131,072
  //   wls_bf :    131,072
  //   h_bf   :  1,048,576
  //   zbf    :    524,288  (z * log2e, bf16)
  //   S      :      8,192
  //   base   :      8,192
  //   ebv_g  :    200,704  (exp(b_vocab), fp32; 0 on pad)
  char* ws = (char*)d_ws;
  unsigned short* wv_bf  = (unsigned short*)(ws);
  unsigned short* we_bf  = (unsigned short*)(ws + 12845056);
  unsigned short* wls_bf = (unsigned short*)(ws + 12845056 + 131072);
  unsigned short* h_bf   = (unsigned short*)(ws + 12845056 + 2 * 131072);
  unsigned short* zbf    = (unsigned short*)(ws + 12845056 + 2 * 131072 + 1048576);
  float*          S      = (float*)(ws + 12845056 + 2 * 131072 + 1048576 + 524288);
  float*          base   = (float*)(ws + 12845056 + 2 * 131072 + 1048576 + 524288 + 8192);
  float*          ebv_g  = (float*)(ws + 12845056 + 2 * 131072 + 1048576 + 524288 + 2 * 8192);

  hipLaunchKernelGGL(convert_all_kernel, dim3(1024), dim3(256), 0, stream,
                     W_vocab, W_enc, W_loc, W_scale, b_vocab,
                     (ushort4*)wv_bf, (ushort4*)we_bf, (ushort4*)wls_bf, ebv_g, S);
  hipLaunchKernelGGL(enc_mfma_kernel, dim3(BB / 2), dim3(256), 0, stream,
                     center_id, context_ids, embeddings, we_bf, b_enc, h_bf);
  hipLaunchKernelGGL(ls_post_kernel, dim3(BB / 8), dim3(256), 0, stream,
                     center_id, context_ids, eps, prior_locs, prior_scales,
                     h_bf, wls_bf, b_loc, b_scale, wv_bf, b_vocab, zbf, base);
  hipLaunchKernelGGL(logits_mfma_kernel, dim3(NWG), dim3(256), 0, stream,
                     zbf, wv_bf, ebv_g, S);
  hipLaunchKernelGGL(fin_kernel, dim3(1), dim3(256), 0, stream, S, base, out);
}